// Round 1
// baseline (21324.998 us; speedup 1.0000x reference)
//
#include <hip/hip_runtime.h>
#include <hip/hip_cooperative_groups.h>
#include <cstddef>

namespace cg = cooperative_groups;

#define BB 256
#define TT 256
#define UU 512
#define MM 64
#define NT 512

// Persistent cooperative kernel.
// Phase 1 (per-batch, block b owns batch b): write_w(t-1), mem update (mem in
// 64 VGPRs/thread: thread u holds mem[b, 0..63, u]), column-sum -> mean,
// logits (LDS partial dots), softmax (wave 0), attended -> ws_att.
// Phase 2 (blocks re-tiled 16x16): transformed = relu(att @ Wt + bt) via
// LDS-tiled fp32 GEMM; writes out[b,t,:] and ws_tr.
__global__ __launch_bounds__(NT, 2) void dnc_kernel(
    const float* __restrict__ x,     // [B,T,U]
    const float* __restrict__ mem0,  // [B, M*U]
    const float* __restrict__ Wr,    // [U, M+1]
    const float* __restrict__ br,    // [M+1]
    const float* __restrict__ Wt,    // [U, U]
    const float* __restrict__ bt,    // [U]
    const float* __restrict__ Ww,    // [U, M]
    const float* __restrict__ bw,    // [M]
    float* __restrict__ out,         // [B,T,U]
    float* __restrict__ ws_att,      // [B,U]
    float* __restrict__ ws_tr)       // [B,U]
{
    cg::grid_group grid = cg::this_grid();
    const int b   = blockIdx.x;   // batch row owned in phase 1
    const int tid = threadIdx.x;  // 0..511
    const int u   = tid;          // memory column owned

    // phase-2 tile coords: 16 row-tiles (16 rows) x 16 col-tiles (32 cols)
    const int rt    = blockIdx.x >> 4;
    const int ct    = blockIdx.x & 15;
    const int r_loc = tid >> 5;   // 0..15
    const int c_loc = tid & 31;   // 0..31

    // register-resident memory column mem[b, m, u]
    float memc[MM];
#pragma unroll
    for (int m = 0; m < MM; ++m)
        memc[m] = mem0[(size_t)b * (MM * UU) + (size_t)m * UU + u];

    __shared__ float lds_mean[UU];      // 2 KB
    __shared__ float lds_tr[UU];        // 2 KB
    __shared__ float lds_part[65 * 8];  // logits partials
    __shared__ float lds_rw[MM + 1];    // read weights
    __shared__ float lds_ww[MM];        // write weights
    __shared__ float lds_wpart[MM * 8]; // write_w partials
    __shared__ float lds_A[16][UU];     // 32 KB attended tile
    __shared__ float lds_W[64][32];     // 8 KB Wt chunk

    for (int t = 0; t < TT; ++t) {
        // ---------------- phase 1 (per-b) ----------------
        float xv = x[(size_t)b * TT * UU + (size_t)t * UU + u];

        if (t > 0) {
            float trv = ws_tr[b * UU + u];
            lds_tr[u] = trv;
            __syncthreads();
            // write_w(t-1)[m] = sigmoid(sum_k tr[k]*Ww[k,m] + bw[m])
            {
                int m = tid >> 3;  // 0..63
                int c = tid & 7;   // 0..7
                float p = 0.f;
                const float* wp = Ww + (size_t)(c * 64) * MM + m;
#pragma unroll 8
                for (int k = 0; k < 64; ++k)
                    p += lds_tr[c * 64 + k] * wp[(size_t)k * MM];
                lds_wpart[m * 8 + c] = p;
            }
            __syncthreads();
            if (tid < MM) {
                float s = 0.f;
#pragma unroll
                for (int c = 0; c < 8; ++c) s += lds_wpart[tid * 8 + c];
                s += bw[tid];
                lds_ww[tid] = 1.f / (1.f + __expf(-s));
            }
            __syncthreads();
            // mem update (registers)
            float trv_u = trv;
#pragma unroll
            for (int m = 0; m < MM; ++m) {
                float w = lds_ww[m];
                memc[m] = (1.f - w) * memc[m] + w * trv_u;
            }
        }

        // column sum -> mean
        float colsum = 0.f;
#pragma unroll
        for (int m = 0; m < MM; ++m) colsum += memc[m];
        float meanv = (colsum + xv) * (1.f / 65.f);
        lds_mean[u] = meanv;
        __syncthreads();

        // logits partials: j = tid>>3 in 0..63, chunk c = tid&7 (64 elems each)
        {
            int j = tid >> 3;
            int c = tid & 7;
            float p = 0.f;
#pragma unroll 8
            for (int k = 0; k < 64; ++k)
                p += lds_mean[c * 64 + k] * Wr[(size_t)(c * 64 + k) * 65 + j];
            lds_part[j * 8 + c] = p;
        }
        if (tid < 8) {  // column j = 64
            int c = tid;
            float p = 0.f;
#pragma unroll 8
            for (int k = 0; k < 64; ++k)
                p += lds_mean[c * 64 + k] * Wr[(size_t)(c * 64 + k) * 65 + 64];
            lds_part[64 * 8 + c] = p;
        }
        __syncthreads();

        // reduce + softmax over 65 on wave 0
        if (tid < 64) {
            float lj = 0.f;
#pragma unroll
            for (int c = 0; c < 8; ++c) lj += lds_part[tid * 8 + c];
            lj += br[tid];
            float l64 = 0.f;
            if (tid == 0) {
#pragma unroll
                for (int c = 0; c < 8; ++c) l64 += lds_part[64 * 8 + c];
                l64 += br[64];
            }
            float mx = lj;
            if (tid == 0) mx = fmaxf(mx, l64);
#pragma unroll
            for (int o = 32; o >= 1; o >>= 1) mx = fmaxf(mx, __shfl_xor(mx, o, 64));
            float e = __expf(lj - mx);
            float e64 = (tid == 0) ? __expf(l64 - mx) : 0.f;
            float sm = e + e64;
#pragma unroll
            for (int o = 32; o >= 1; o >>= 1) sm += __shfl_xor(sm, o, 64);
            lds_rw[tid] = e / sm;
            if (tid == 0) lds_rw[64] = e64 / sm;
        }
        __syncthreads();

        // attended
        float att = lds_rw[MM] * xv;
#pragma unroll
        for (int m = 0; m < MM; ++m) att += lds_rw[m] * memc[m];
        ws_att[b * UU + u] = att;

        grid.sync();

        // ---------------- phase 2 (tiled GEMM) ----------------
        // stage A tile: rows rt*16 .. rt*16+15, all 512 cols (32 KB)
        {
            const float4* src = reinterpret_cast<const float4*>(ws_att + (size_t)(rt * 16) * UU);
            float4* dst = reinterpret_cast<float4*>(&lds_A[0][0]);
#pragma unroll
            for (int i = 0; i < 4; ++i) dst[tid + i * NT] = src[tid + i * NT];
        }

        float acc = 0.f;
        for (int k0 = 0; k0 < UU; k0 += 64) {
            __syncthreads();
            // stage Wt[k0..k0+63][ct*32 .. ct*32+31]
#pragma unroll
            for (int i = 0; i < 4; ++i) {
                int l = tid + i * NT;
                int kk = l >> 5, cc = l & 31;
                lds_W[kk][cc] = Wt[(size_t)(k0 + kk) * UU + ct * 32 + cc];
            }
            __syncthreads();
#pragma unroll 16
            for (int kk = 0; kk < 64; ++kk)
                acc += lds_A[r_loc][k0 + kk] * lds_W[kk][c_loc];
        }

        int row = rt * 16 + r_loc;  // batch index
        int col = ct * 32 + c_loc;  // u index
        float tr = acc + bt[col];
        tr = fmaxf(tr, 0.f);
        ws_tr[row * UU + col] = tr;
        out[(size_t)row * TT * UU + (size_t)t * UU + col] = tr;

        grid.sync();
    }
}

extern "C" void kernel_launch(void* const* d_in, const int* in_sizes, int n_in,
                              void* d_out, int out_size, void* d_ws, size_t ws_size,
                              hipStream_t stream) {
    const float* x    = (const float*)d_in[0];
    const float* mem0 = (const float*)d_in[1];
    const float* Wr   = (const float*)d_in[2];
    const float* br   = (const float*)d_in[3];
    const float* Wt   = (const float*)d_in[4];
    const float* bt   = (const float*)d_in[5];
    const float* Ww   = (const float*)d_in[6];
    const float* bw   = (const float*)d_in[7];
    float* out = (float*)d_out;

    float* ws_att = (float*)d_ws;             // [B,U]
    float* ws_tr  = ws_att + BB * UU;         // [B,U]

    void* args[] = {(void*)&x, (void*)&mem0, (void*)&Wr, (void*)&br,
                    (void*)&Wt, (void*)&bt, (void*)&Ww, (void*)&bw,
                    (void*)&out, (void*)&ws_att, (void*)&ws_tr};

    hipLaunchCooperativeKernel((const void*)dnc_kernel, dim3(BB), dim3(NT),
                               args, 0, stream);
}